// Round 5
// baseline (184.334 us; speedup 1.0000x reference)
//
#include <hip/hip_runtime.h>
#include <stdint.h>

typedef float    f32x4 __attribute__((ext_vector_type(4)));
typedef _Float16 f16x8 __attribute__((ext_vector_type(8)));
typedef _Float16 f16x4 __attribute__((ext_vector_type(4)));

#define BSZ  32768
#define MHOP 8
#define DDIM 128
#define HDIM 512
#define KD   128     // K per part (q-part and k-part each 128)
#define BT   8       // batches per tile
#define ROWS 64      // BT*MHOP rows per tile
#define NTILE (BSZ / BT)   // 4096 tiles

// ---- prep: W1 fp32 [512][256] -> f16 [512][256] in ws ----
__global__ void prep_w1_f16(const float* __restrict__ W1, _Float16* __restrict__ W1h) {
    int i = (blockIdx.x * blockDim.x + threadIdx.x) * 4;
    float4 v = *reinterpret_cast<const float4*>(W1 + i);
    f16x4 o;
    o[0] = (_Float16)v.x; o[1] = (_Float16)v.y;
    o[2] = (_Float16)v.z; o[3] = (_Float16)v.w;
    *reinterpret_cast<f16x4*>(W1h + i) = o;
}

__device__ __forceinline__ f16x8 cvt_f16x8(float4 x0, float4 x1) {
    f16x8 p;
    p[0]=(_Float16)x0.x; p[1]=(_Float16)x0.y; p[2]=(_Float16)x0.z; p[3]=(_Float16)x0.w;
    p[4]=(_Float16)x1.x; p[5]=(_Float16)x1.y; p[6]=(_Float16)x1.z; p[7]=(_Float16)x1.w;
    return p;
}

// ---- kernel A: per 64-row tile: u = q@W1q^T (8x512, shared via LDS),
//      t = k@W1k^T (64x512), scores = W2 . relu(t + u), softmax over 8 hops,
//      write attn [BSZ][MHOP] f32 to ws. ----
__global__ void __launch_bounds__(512, 4) scores_kernel(
    const float* __restrict__ q_vec,
    const float* __restrict__ k_vec,
    const _Float16* __restrict__ W1h,
    const float* __restrict__ W2,
    float* __restrict__ attn_out)
{
    __shared__ __align__(16) _Float16 a_q[BT * DDIM];     // 8x128 (2 KB)
    __shared__ __align__(16) _Float16 a_k[ROWS * DDIM];   // 64x128 swizzled (16 KB)
    __shared__ float u_lds[BT][HDIM];                     // 16 KB
    __shared__ float scores_part[8][ROWS];                // 2 KB

    const int t  = threadIdx.x;
    const int w  = t >> 6;    // wave 0..7 -> hidden cols [64w, 64w+64)
    const int l  = t & 63;
    const int lg = l >> 4;
    const int ll = l & 15;
    const long b0 = (long)blockIdx.x * BT;

    // ---- stage k tile: 64 rows x 128, fp32 -> f16, chunk-XOR swizzle ----
    #pragma unroll
    for (int cc = 0; cc < 2; ++cc) {
        int cid = t + cc * 512, row = cid >> 4, c = cid & 15;
        const float4* s = reinterpret_cast<const float4*>(
            k_vec + b0 * (MHOP * DDIM) + (size_t)cid * 8);
        float4 x0 = s[0], x1 = s[1];
        *reinterpret_cast<f16x8*>(&a_k[row * DDIM + ((c ^ (row & 7)) * 8)]) = cvt_f16x8(x0, x1);
    }
    // ---- stage q tile: 8 rows x 128 (linear; reads are 8-lane broadcast) ----
    if (t < 128) {
        const float4* s = reinterpret_cast<const float4*>(q_vec + b0 * DDIM + (size_t)t * 8);
        float4 x0 = s[0], x1 = s[1];
        int row = t >> 4, c = t & 15;
        *reinterpret_cast<f16x8*>(&a_q[row * DDIM + c * 8]) = cvt_f16x8(x0, x1);
    }
    __syncthreads();

    // W1h row h: [0..128) = q-part, [128..256) = k-part
    const _Float16* w1q = W1h + (size_t)(w * 64 + ll) * (2 * KD) + lg * 8;
    const _Float16* w1k = w1q + KD;

    // ---- q-GEMM: u[b][h] for this wave's 64 cols (A rows = batches, 8 valid) ----
    {
        f32x4 accu[4] = {};
        #pragma unroll
        for (int kf = 0; kf < 4; ++kf) {
            const int kk = kf * 32 + lg * 8;
            // A-row = ll; duplicate batches for rows 8-15 (discarded)
            f16x8 aq = *reinterpret_cast<const f16x8*>(&a_q[(ll & 7) * DDIM + kk]);
            #pragma unroll
            for (int fc = 0; fc < 4; ++fc) {
                f16x8 bq = *reinterpret_cast<const f16x8*>(
                    w1q + (size_t)(fc * 16) * (2 * KD) + kf * 32);
                accu[fc] = __builtin_amdgcn_mfma_f32_16x16x32_f16(aq, bq, accu[fc], 0, 0, 0);
            }
        }
        // C rows = lg*4+j (= batch), cols = ll; keep rows < 8
        if (lg < 2) {
            #pragma unroll
            for (int fc = 0; fc < 4; ++fc)
                #pragma unroll
                for (int j = 0; j < 4; ++j)
                    u_lds[lg * 4 + j][w * 64 + fc * 16 + ll] = accu[fc][j];
        }
    }
    // no barrier needed: each wave reads back only its own u_lds columns

    // ---- k-GEMM: 64 rows x 64 cols/wave, K=128 ----
    f32x4 acc[4][4] = {};
    #pragma unroll
    for (int kf = 0; kf < 4; ++kf) {
        const int kk = kf * 32 + lg * 8;
        f16x8 bfrag[4];
        #pragma unroll
        for (int fc = 0; fc < 4; ++fc)
            bfrag[fc] = *reinterpret_cast<const f16x8*>(
                w1k + (size_t)(fc * 16) * (2 * KD) + kf * 32);
        #pragma unroll
        for (int fr = 0; fr < 4; ++fr) {
            int row = fr * 16 + ll;
            int chunk = kf * 4 + lg;
            f16x8 af = *reinterpret_cast<const f16x8*>(
                &a_k[row * DDIM + ((chunk ^ (row & 7)) * 8)]);
            #pragma unroll
            for (int fc = 0; fc < 4; ++fc)
                acc[fr][fc] = __builtin_amdgcn_mfma_f32_16x16x32_f16(af, bfrag[fc], acc[fr][fc], 0, 0, 0);
        }
    }

    // ---- epilogue: s(row) = sum_h W2[h] * relu(t + u), partial over 64 cols ----
    float w2r[4];
    #pragma unroll
    for (int fc = 0; fc < 4; ++fc) w2r[fc] = W2[w * 64 + fc * 16 + ll];

    #pragma unroll
    for (int fr = 0; fr < 4; ++fr) {
        #pragma unroll
        for (int j = 0; j < 4; ++j) {
            int row = fr * 16 + lg * 4 + j;
            int b = row >> 3;
            float s = 0.f;
            #pragma unroll
            for (int fc = 0; fc < 4; ++fc) {
                float val = acc[fr][fc][j] + u_lds[b][w * 64 + fc * 16 + ll];
                s += w2r[fc] * fmaxf(val, 0.f);
            }
            s += __shfl_xor(s, 1);
            s += __shfl_xor(s, 2);
            s += __shfl_xor(s, 4);
            s += __shfl_xor(s, 8);
            if (ll == 0) scores_part[w][row] = s;
        }
    }
    __syncthreads();

    // ---- cross-wave reduce + softmax over the 8 hops; write attn ----
    if (t < ROWS) {
        float s = 0.f;
        #pragma unroll
        for (int ww = 0; ww < 8; ++ww) s += scores_part[ww][t];
        float mx = s;
        mx = fmaxf(mx, __shfl_xor(mx, 1, 8));
        mx = fmaxf(mx, __shfl_xor(mx, 2, 8));
        mx = fmaxf(mx, __shfl_xor(mx, 4, 8));
        float e = __expf(s - mx);
        float sum = e;
        sum += __shfl_xor(sum, 1, 8);
        sum += __shfl_xor(sum, 2, 8);
        sum += __shfl_xor(sum, 4, 8);
        attn_out[b0 * MHOP + t] = e / sum;
    }
}

// ---- kernel B: out[b][d] = sum_m attn[b][m] * v[b][m][d] (pure streaming) ----
__global__ void __launch_bounds__(256) out_kernel(
    const float* __restrict__ v_vec,
    const float* __restrict__ attn,
    float* __restrict__ out)
{
    __shared__ float attn_lds[64];
    const int t = threadIdx.x;
    const long b0 = (long)blockIdx.x * 8;
    if (t < 64) attn_lds[t] = attn[b0 * MHOP + t];
    __syncthreads();

    const int b = t >> 5;          // 0..7
    const int d = (t & 31) * 4;    // 0..124
    const float* vb = v_vec + (b0 + b) * (MHOP * DDIM) + d;
    float a0 = 0.f, a1 = 0.f, a2 = 0.f, a3 = 0.f;
    #pragma unroll
    for (int m = 0; m < MHOP; ++m) {
        float at = attn_lds[b * 8 + m];
        float4 vv = *reinterpret_cast<const float4*>(vb + m * DDIM);
        a0 += at * vv.x; a1 += at * vv.y; a2 += at * vv.z; a3 += at * vv.w;
    }
    float4 o; o.x = a0; o.y = a1; o.z = a2; o.w = a3;
    *reinterpret_cast<float4*>(out + (b0 + b) * DDIM + d) = o;
}

extern "C" void kernel_launch(void* const* d_in, const int* in_sizes, int n_in,
                              void* d_out, int out_size, void* d_ws, size_t ws_size,
                              hipStream_t stream) {
    const float* q  = (const float*)d_in[0];
    const float* k  = (const float*)d_in[1];
    const float* v  = (const float*)d_in[2];
    const float* W1 = (const float*)d_in[3];
    const float* W2 = (const float*)d_in[4];

    _Float16* W1h = (_Float16*)d_ws;                              // 256 KB
    float* attn   = (float*)((char*)d_ws + (size_t)HDIM * 2 * KD * 2); // 1 MB

    prep_w1_f16<<<(HDIM * 2 * KD) / (256 * 4), 256, 0, stream>>>(W1, W1h);
    scores_kernel<<<NTILE, 512, 0, stream>>>(q, k, W1h, W2, attn);
    out_kernel<<<BSZ / 8, 256, 0, stream>>>(v, attn, (float*)d_out);
}

// Round 6
// 128.798 us; speedup vs baseline: 1.4312x; 1.4312x over previous
//
#include <hip/hip_runtime.h>
#include <stdint.h>

typedef float    f32x4 __attribute__((ext_vector_type(4)));
typedef _Float16 f16x8 __attribute__((ext_vector_type(8)));
typedef _Float16 f16x4 __attribute__((ext_vector_type(4)));

#define BSZ  32768
#define MHOP 8
#define DDIM 128
#define HDIM 512
#define BT   8        // batches per tile
#define ROWS 64       // BT*MHOP rows per tile
#define NT   8        // tiles per block
#define NBLK 512      // NBLK*NT*BT == BSZ
#define AQLD 136      // padded a_q row stride (f16) to break bank conflicts

// ---- prep: split W1 [512][256] f32 into W1q/W1k [512][128] f16 ----
__global__ void prep_w1(const float* __restrict__ W1,
                        _Float16* __restrict__ W1q, _Float16* __restrict__ W1k) {
    int i = (blockIdx.x * blockDim.x + threadIdx.x) * 4;   // over 512*256
    float4 v = *reinterpret_cast<const float4*>(W1 + i);
    f16x4 o;
    o[0]=(_Float16)v.x; o[1]=(_Float16)v.y; o[2]=(_Float16)v.z; o[3]=(_Float16)v.w;
    int h = i >> 8, c = i & 255;
    _Float16* dst = (c < 128) ? (W1q + h * 128 + c) : (W1k + h * 128 + (c - 128));
    *reinterpret_cast<f16x4*>(dst) = o;
}

__device__ __forceinline__ f16x8 cvt_f16x8(float4 x0, float4 x1) {
    f16x8 p;
    p[0]=(_Float16)x0.x; p[1]=(_Float16)x0.y; p[2]=(_Float16)x0.z; p[3]=(_Float16)x0.w;
    p[4]=(_Float16)x1.x; p[5]=(_Float16)x1.y; p[6]=(_Float16)x1.z; p[7]=(_Float16)x1.w;
    return p;
}

// ---- kernel A (persistent): W1k in LDS, W1q in regs; per tile:
//      u = q@W1q^T (regs->u_lds), t = k@W1k^T, s = W2.relu(t+u), softmax(8) ----
__global__ void __launch_bounds__(512, 2) scores_kernel(
    const float* __restrict__ q_vec,
    const float* __restrict__ k_vec,
    const _Float16* __restrict__ W1q,
    const _Float16* __restrict__ W1k,
    const float* __restrict__ W2,
    float* __restrict__ attn_out)
{
    __shared__ __align__(16) _Float16 w1k_lds[HDIM * DDIM];  // 128 KB, swizzled
    __shared__ __align__(16) _Float16 a_k[ROWS * DDIM];      // 16 KB, swizzled
    __shared__ __align__(16) _Float16 a_q[BT * AQLD];        // 2.125 KB, padded
    __shared__ _Float16 u_lds[BT * HDIM];                    // 8 KB
    __shared__ float scores_part[8][ROWS];                   // 2 KB
    // total ~156.3 KB -> 1 block/CU

    const int t  = threadIdx.x;
    const int w  = t >> 6;     // wave id: hidden cols [64w, 64w+64)
    const int l  = t & 63;
    const int lg = l >> 4;
    const int ll = l & 15;
    const long tile0 = (long)blockIdx.x * NT;

    // ---- stage W1k -> LDS once (coalesced 16B, XOR-swizzled rows) ----
    #pragma unroll
    for (int i2 = 0; i2 < 16; ++i2) {
        int cid = i2 * 512 + t;                 // 8192 chunks of 8 f16
        int row = cid >> 4, c = cid & 15;
        f16x8 p = *reinterpret_cast<const f16x8*>(W1k + (size_t)cid * 8);
        *reinterpret_cast<f16x8*>(&w1k_lds[row * DDIM + ((c ^ (row & 7)) * 8)]) = p;
    }

    // ---- W1q slice for this wave: 16 frags = 64 VGPR, loaded once ----
    f16x8 w1qf[4][4];
    {
        const _Float16* base = W1q + (size_t)(w * 64 + ll) * DDIM + lg * 8;
        #pragma unroll
        for (int kf = 0; kf < 4; ++kf)
            #pragma unroll
            for (int fc = 0; fc < 4; ++fc)
                w1qf[kf][fc] = *reinterpret_cast<const f16x8*>(
                    base + (size_t)(fc * 16) * DDIM + kf * 32);
    }
    float w2r[4];
    #pragma unroll
    for (int fc = 0; fc < 4; ++fc) w2r[fc] = W2[w * 64 + fc * 16 + ll];

    // ---- prologue: prefetch tile 0 (k: 16 floats/thread, q: 8 floats) ----
    float4 kr[2][2]; float4 qr[2];
    {
        const long b0p = tile0 * BT;
        const float4* ks = reinterpret_cast<const float4*>(k_vec + b0p * (MHOP * DDIM));
        kr[0][0] = ks[t * 2];         kr[0][1] = ks[t * 2 + 1];
        kr[1][0] = ks[(t + 512) * 2]; kr[1][1] = ks[(t + 512) * 2 + 1];
        if (t < 128) {
            const float4* qs = reinterpret_cast<const float4*>(q_vec + b0p * DDIM);
            qr[0] = qs[t * 2]; qr[1] = qs[t * 2 + 1];
        }
    }

    for (int it = 0; it < NT; ++it) {
        const long b0 = tile0 * BT + (long)it * BT;

        // ---- stage current tile from prefetch regs (cvt to f16) ----
        #pragma unroll
        for (int cc = 0; cc < 2; ++cc) {
            int cid = t + cc * 512, row = cid >> 4, c = cid & 15;
            *reinterpret_cast<f16x8*>(&a_k[row * DDIM + ((c ^ (row & 7)) * 8)]) =
                cvt_f16x8(kr[cc][0], kr[cc][1]);
        }
        if (t < 128) {
            int row = t >> 4, c = t & 15;
            *reinterpret_cast<f16x8*>(&a_q[row * AQLD + c * 8]) = cvt_f16x8(qr[0], qr[1]);
        }
        __syncthreads();   // bar1: a_k/a_q (and on it=0, w1k_lds) visible

        // ---- issue next tile's global loads; land during MFMA ----
        if (it + 1 < NT) {
            const long bn = b0 + BT;
            const float4* ks = reinterpret_cast<const float4*>(k_vec + bn * (MHOP * DDIM));
            kr[0][0] = ks[t * 2];         kr[0][1] = ks[t * 2 + 1];
            kr[1][0] = ks[(t + 512) * 2]; kr[1][1] = ks[(t + 512) * 2 + 1];
            if (t < 128) {
                const float4* qs = reinterpret_cast<const float4*>(q_vec + bn * DDIM);
                qr[0] = qs[t * 2]; qr[1] = qs[t * 2 + 1];
            }
        }

        // ---- q-GEMM: u (8 rows x this wave's 64 cols), B from regs ----
        {
            f32x4 accu[4] = {};
            #pragma unroll
            for (int kf = 0; kf < 4; ++kf) {
                const int kk = kf * 32 + lg * 8;
                f16x8 aq = *reinterpret_cast<const f16x8*>(&a_q[(ll & 7) * AQLD + kk]);
                #pragma unroll
                for (int fc = 0; fc < 4; ++fc)
                    accu[fc] = __builtin_amdgcn_mfma_f32_16x16x32_f16(aq, w1qf[kf][fc], accu[fc], 0, 0, 0);
            }
            if (lg < 2) {
                #pragma unroll
                for (int fc = 0; fc < 4; ++fc)
                    #pragma unroll
                    for (int j = 0; j < 4; ++j)
                        u_lds[(lg * 4 + j) * HDIM + w * 64 + fc * 16 + ll] =
                            (_Float16)accu[fc][j];
            }
        }
        // no barrier: each wave reads back only its own u columns

        // ---- k-GEMM: 64 rows x 64 cols/wave, K=128, B from LDS ----
        f32x4 acc[4][4] = {};
        #pragma unroll
        for (int kf = 0; kf < 4; ++kf) {
            f16x8 bf[4];
            #pragma unroll
            for (int fc = 0; fc < 4; ++fc) {
                int hrow = w * 64 + fc * 16 + ll;
                int ch = kf * 4 + lg;
                bf[fc] = *reinterpret_cast<const f16x8*>(
                    &w1k_lds[hrow * DDIM + ((ch ^ (hrow & 7)) * 8)]);
            }
            #pragma unroll
            for (int fr = 0; fr < 4; ++fr) {
                int row = fr * 16 + ll;
                int ch = kf * 4 + lg;
                f16x8 af = *reinterpret_cast<const f16x8*>(
                    &a_k[row * DDIM + ((ch ^ (row & 7)) * 8)]);
                #pragma unroll
                for (int fc = 0; fc < 4; ++fc)
                    acc[fr][fc] = __builtin_amdgcn_mfma_f32_16x16x32_f16(af, bf[fc], acc[fr][fc], 0, 0, 0);
            }
        }

        // ---- epilogue: s(row) = sum_h W2[h]*relu(t + u), 16-lane reduce ----
        #pragma unroll
        for (int fr = 0; fr < 4; ++fr) {
            const int b = fr * 2 + (lg >> 1);
            #pragma unroll
            for (int j = 0; j < 4; ++j) {
                float s = 0.f;
                #pragma unroll
                for (int fc = 0; fc < 4; ++fc) {
                    float uval = (float)u_lds[b * HDIM + w * 64 + fc * 16 + ll];
                    s += w2r[fc] * fmaxf(acc[fr][fc][j] + uval, 0.f);
                }
                s += __shfl_xor(s, 1);
                s += __shfl_xor(s, 2);
                s += __shfl_xor(s, 4);
                s += __shfl_xor(s, 8);
                if (ll == 0) scores_part[w][fr * 16 + lg * 4 + j] = s;
            }
        }
        __syncthreads();   // bar2

        // ---- softmax over 8 hops; write attn ----
        if (t < ROWS) {
            float s = 0.f;
            #pragma unroll
            for (int ww = 0; ww < 8; ++ww) s += scores_part[ww][t];
            float mx = s;
            mx = fmaxf(mx, __shfl_xor(mx, 1, 8));
            mx = fmaxf(mx, __shfl_xor(mx, 2, 8));
            mx = fmaxf(mx, __shfl_xor(mx, 4, 8));
            float e = __expf(s - mx);
            float sum = e;
            sum += __shfl_xor(sum, 1, 8);
            sum += __shfl_xor(sum, 2, 8);
            sum += __shfl_xor(sum, 4, 8);
            attn_out[b0 * MHOP + t] = e / sum;
        }
        // next iteration's LDS writes are ordered behind bar1(it+1); softmax
        // threads reach it only after their reads -> no extra barrier needed
    }
}

// ---- kernel B: out[b][d] = sum_m attn[b][m] * v[b][m][d] (streaming) ----
__global__ void __launch_bounds__(256) out_kernel(
    const float* __restrict__ v_vec,
    const float* __restrict__ attn,
    float* __restrict__ out)
{
    __shared__ float attn_lds[64];
    const int t = threadIdx.x;
    const long b0 = (long)blockIdx.x * 8;
    if (t < 64) attn_lds[t] = attn[b0 * MHOP + t];
    __syncthreads();

    const int b = t >> 5;
    const int d = (t & 31) * 4;
    const float* vb = v_vec + (b0 + b) * (MHOP * DDIM) + d;
    float a0 = 0.f, a1 = 0.f, a2 = 0.f, a3 = 0.f;
    #pragma unroll
    for (int m = 0; m < MHOP; ++m) {
        float at = attn_lds[b * 8 + m];
        float4 vv = *reinterpret_cast<const float4*>(vb + m * DDIM);
        a0 += at * vv.x; a1 += at * vv.y; a2 += at * vv.z; a3 += at * vv.w;
    }
    float4 o; o.x = a0; o.y = a1; o.z = a2; o.w = a3;
    *reinterpret_cast<float4*>(out + (b0 + b) * DDIM + d) = o;
}

extern "C" void kernel_launch(void* const* d_in, const int* in_sizes, int n_in,
                              void* d_out, int out_size, void* d_ws, size_t ws_size,
                              hipStream_t stream) {
    const float* q  = (const float*)d_in[0];
    const float* k  = (const float*)d_in[1];
    const float* v  = (const float*)d_in[2];
    const float* W1 = (const float*)d_in[3];
    const float* W2 = (const float*)d_in[4];

    _Float16* W1q = (_Float16*)d_ws;                                   // 128 KB
    _Float16* W1k = (_Float16*)((char*)d_ws + 128 * 1024);             // 128 KB
    float*    attn = (float*)((char*)d_ws + 256 * 1024);               // 1 MB

    prep_w1<<<(HDIM * 256) / (256 * 4), 256, 0, stream>>>(W1, W1q, W1k);
    scores_kernel<<<NBLK, 512, 0, stream>>>(q, k, W1q, W1k, W2, attn);
    out_kernel<<<BSZ / 8, 256, 0, stream>>>(v, attn, (float*)d_out);
}

// Round 7
// 115.199 us; speedup vs baseline: 1.6001x; 1.1180x over previous
//
#include <hip/hip_runtime.h>
#include <stdint.h>

typedef float    f32x4 __attribute__((ext_vector_type(4)));
typedef _Float16 f16x8 __attribute__((ext_vector_type(8)));
typedef _Float16 f16x4 __attribute__((ext_vector_type(4)));

#define BSZ  32768
#define MHOP 8
#define DDIM 128
#define HDIM 512
#define BT   8        // batches per tile
#define ROWS 64       // BT*MHOP rows per tile
#define NT   16       // tiles per block
#define NBLK 256      // NBLK*NT*BT == BSZ ; 1 block per CU
#define AQLD 136      // padded a_q row stride (f16)

// ---- prep: split W1 [512][256] f32 into W1q/W1k [512][128] f16 ----
__global__ void prep_w1(const float* __restrict__ W1,
                        _Float16* __restrict__ W1q, _Float16* __restrict__ W1k) {
    int i = (blockIdx.x * blockDim.x + threadIdx.x) * 4;   // over 512*256
    float4 v = *reinterpret_cast<const float4*>(W1 + i);
    f16x4 o;
    o[0]=(_Float16)v.x; o[1]=(_Float16)v.y; o[2]=(_Float16)v.z; o[3]=(_Float16)v.w;
    int h = i >> 8, c = i & 255;
    _Float16* dst = (c < 128) ? (W1q + h * 128 + c) : (W1k + h * 128 + (c - 128));
    *reinterpret_cast<f16x4*>(dst) = o;
}

__device__ __forceinline__ f16x8 cvt_f16x8(float4 x0, float4 x1) {
    f16x8 p;
    p[0]=(_Float16)x0.x; p[1]=(_Float16)x0.y; p[2]=(_Float16)x0.z; p[3]=(_Float16)x0.w;
    p[4]=(_Float16)x1.x; p[5]=(_Float16)x1.y; p[6]=(_Float16)x1.z; p[7]=(_Float16)x1.w;
    return p;
}

// ---- fused persistent kernel: W1k in LDS, W1q in regs; per tile:
//      u = q@W1q^T; t = k@W1k^T; s = W2.relu(t+u); softmax(8); out = attn@v ----
__global__ void __launch_bounds__(512, 2) fused_kernel(
    const float* __restrict__ q_vec,
    const float* __restrict__ k_vec,
    const float* __restrict__ v_vec,
    const _Float16* __restrict__ W1q,
    const _Float16* __restrict__ W1k,
    const float* __restrict__ W2,
    float* __restrict__ out)
{
    __shared__ __align__(16) _Float16 w1k_lds[HDIM * DDIM];  // 128 KB, swizzled
    __shared__ __align__(16) _Float16 a_k[ROWS * DDIM];      // 16 KB, swizzled
    __shared__ __align__(16) _Float16 a_q[BT * AQLD];        // 2.125 KB
    __shared__ _Float16 u_lds[BT * HDIM];                    // 8 KB
    __shared__ float scores_part[8][ROWS];                   // 2 KB
    __shared__ float attn_lds[ROWS];                         // 256 B
    // total ~156.4 KB -> 1 block/CU

    const int t  = threadIdx.x;
    const int w  = t >> 6;     // wave id: hidden cols [64w, 64w+64)
    const int l  = t & 63;
    const int lg = l >> 4;
    const int ll = l & 15;
    const long tile0 = (long)blockIdx.x * NT;

    // ---- stage W1k -> LDS once (coalesced 16B, XOR-swizzled rows) ----
    #pragma unroll
    for (int i2 = 0; i2 < 16; ++i2) {
        int cid = i2 * 512 + t;
        int row = cid >> 4, c = cid & 15;
        f16x8 p = *reinterpret_cast<const f16x8*>(W1k + (size_t)cid * 8);
        *reinterpret_cast<f16x8*>(&w1k_lds[row * DDIM + ((c ^ (row & 7)) * 8)]) = p;
    }

    // ---- W1q slice for this wave: 16 frags = 64 VGPR, loaded once ----
    f16x8 w1qf[4][4];
    {
        const _Float16* base = W1q + (size_t)(w * 64 + ll) * DDIM + lg * 8;
        #pragma unroll
        for (int kf = 0; kf < 4; ++kf)
            #pragma unroll
            for (int fc = 0; fc < 4; ++fc)
                w1qf[kf][fc] = *reinterpret_cast<const f16x8*>(
                    base + (size_t)(fc * 16) * DDIM + kf * 32);
    }
    float w2r[4];
    #pragma unroll
    for (int fc = 0; fc < 4; ++fc) w2r[fc] = W2[w * 64 + fc * 16 + ll];

    // ---- prologue: prefetch tile 0 ----
    float4 kr[2][2]; float4 qr[2];
    {
        const long b0p = tile0 * BT;
        const float4* ks = reinterpret_cast<const float4*>(k_vec + b0p * (MHOP * DDIM));
        kr[0][0] = ks[t * 2];         kr[0][1] = ks[t * 2 + 1];
        kr[1][0] = ks[(t + 512) * 2]; kr[1][1] = ks[(t + 512) * 2 + 1];
        if (t < 128) {
            const float4* qs = reinterpret_cast<const float4*>(q_vec + b0p * DDIM);
            qr[0] = qs[t * 2]; qr[1] = qs[t * 2 + 1];
        }
    }

    for (int it = 0; it < NT; ++it) {
        const long b0 = tile0 * BT + (long)it * BT;

        // ---- stage current tile from prefetch regs ----
        #pragma unroll
        for (int cc = 0; cc < 2; ++cc) {
            int cid = t + cc * 512, row = cid >> 4, c = cid & 15;
            *reinterpret_cast<f16x8*>(&a_k[row * DDIM + ((c ^ (row & 7)) * 8)]) =
                cvt_f16x8(kr[cc][0], kr[cc][1]);
        }
        if (t < 128) {
            int row = t >> 4, c = t & 15;
            *reinterpret_cast<f16x8*>(&a_q[row * AQLD + c * 8]) = cvt_f16x8(qr[0], qr[1]);
        }
        __syncthreads();   // bar1

        // ---- issue next tile's k/q loads + this tile's v loads ----
        if (it + 1 < NT) {
            const long bn = b0 + BT;
            const float4* ks = reinterpret_cast<const float4*>(k_vec + bn * (MHOP * DDIM));
            kr[0][0] = ks[t * 2];         kr[0][1] = ks[t * 2 + 1];
            kr[1][0] = ks[(t + 512) * 2]; kr[1][1] = ks[(t + 512) * 2 + 1];
            if (t < 128) {
                const float4* qs = reinterpret_cast<const float4*>(q_vec + bn * DDIM);
                qr[0] = qs[t * 2]; qr[1] = qs[t * 2 + 1];
            }
        }
        float2 vr[8];
        {
            const float* vb = v_vec + (b0 + w) * (MHOP * DDIM) + l * 2;
            #pragma unroll
            for (int m = 0; m < MHOP; ++m)
                vr[m] = *reinterpret_cast<const float2*>(vb + m * DDIM);
        }

        // ---- q-GEMM: u (8 rows x this wave's 64 cols), B from regs ----
        {
            f32x4 accu[4] = {};
            #pragma unroll
            for (int kf = 0; kf < 4; ++kf) {
                const int kk = kf * 32 + lg * 8;
                f16x8 aq = *reinterpret_cast<const f16x8*>(&a_q[(ll & 7) * AQLD + kk]);
                #pragma unroll
                for (int fc = 0; fc < 4; ++fc)
                    accu[fc] = __builtin_amdgcn_mfma_f32_16x16x32_f16(aq, w1qf[kf][fc], accu[fc], 0, 0, 0);
            }
            if (lg < 2) {
                #pragma unroll
                for (int fc = 0; fc < 4; ++fc)
                    #pragma unroll
                    for (int j = 0; j < 4; ++j)
                        u_lds[(lg * 4 + j) * HDIM + w * 64 + fc * 16 + ll] =
                            (_Float16)accu[fc][j];
            }
        }
        // no barrier: each wave reads back only its own u columns

        // ---- k-GEMM: 64 rows x 64 cols/wave, K=128, B from LDS ----
        f32x4 acc[4][4] = {};
        #pragma unroll
        for (int kf = 0; kf < 4; ++kf) {
            f16x8 bf[4];
            #pragma unroll
            for (int fc = 0; fc < 4; ++fc) {
                int hrow = w * 64 + fc * 16 + ll;
                int ch = kf * 4 + lg;
                bf[fc] = *reinterpret_cast<const f16x8*>(
                    &w1k_lds[hrow * DDIM + ((ch ^ (hrow & 7)) * 8)]);
            }
            #pragma unroll
            for (int fr = 0; fr < 4; ++fr) {
                int row = fr * 16 + ll;
                int ch = kf * 4 + lg;
                f16x8 af = *reinterpret_cast<const f16x8*>(
                    &a_k[row * DDIM + ((ch ^ (row & 7)) * 8)]);
                #pragma unroll
                for (int fc = 0; fc < 4; ++fc)
                    acc[fr][fc] = __builtin_amdgcn_mfma_f32_16x16x32_f16(af, bf[fc], acc[fr][fc], 0, 0, 0);
            }
        }

        // ---- hoisted u reads: 16 instead of 64 (b is j-invariant) ----
        float uf[4][4];
        #pragma unroll
        for (int fr = 0; fr < 4; ++fr) {
            const int b = fr * 2 + (lg >> 1);
            #pragma unroll
            for (int fc = 0; fc < 4; ++fc)
                uf[fr][fc] = (float)u_lds[b * HDIM + w * 64 + fc * 16 + ll];
        }

        // ---- epilogue: s(row) = sum_h W2[h]*relu(t + u), 16-lane reduce ----
        #pragma unroll
        for (int fr = 0; fr < 4; ++fr) {
            #pragma unroll
            for (int j = 0; j < 4; ++j) {
                float s = 0.f;
                #pragma unroll
                for (int fc = 0; fc < 4; ++fc)
                    s += w2r[fc] * fmaxf(acc[fr][fc][j] + uf[fr][fc], 0.f);
                s += __shfl_xor(s, 1);
                s += __shfl_xor(s, 2);
                s += __shfl_xor(s, 4);
                s += __shfl_xor(s, 8);
                if (ll == 0) scores_part[w][fr * 16 + lg * 4 + j] = s;
            }
        }
        __syncthreads();   // bar2

        // ---- softmax over 8 hops -> attn_lds ----
        if (t < ROWS) {
            float s = 0.f;
            #pragma unroll
            for (int ww = 0; ww < 8; ++ww) s += scores_part[ww][t];
            float mx = s;
            mx = fmaxf(mx, __shfl_xor(mx, 1, 8));
            mx = fmaxf(mx, __shfl_xor(mx, 2, 8));
            mx = fmaxf(mx, __shfl_xor(mx, 4, 8));
            float e = __expf(s - mx);
            float sum = e;
            sum += __shfl_xor(sum, 1, 8);
            sum += __shfl_xor(sum, 2, 8);
            sum += __shfl_xor(sum, 4, 8);
            attn_lds[t] = e / sum;
        }
        __syncthreads();   // bar3

        // ---- output: wave w owns batch b0+w; out[b][d] = sum_m attn*v ----
        {
            float a0 = 0.f, a1 = 0.f;
            #pragma unroll
            for (int m = 0; m < MHOP; ++m) {
                float at = attn_lds[w * 8 + m];   // broadcast within wave
                a0 += at * vr[m].x;
                a1 += at * vr[m].y;
            }
            float2 o; o.x = a0; o.y = a1;
            *reinterpret_cast<float2*>(out + (b0 + w) * DDIM + l * 2) = o;
        }
    }
}

extern "C" void kernel_launch(void* const* d_in, const int* in_sizes, int n_in,
                              void* d_out, int out_size, void* d_ws, size_t ws_size,
                              hipStream_t stream) {
    const float* q  = (const float*)d_in[0];
    const float* k  = (const float*)d_in[1];
    const float* v  = (const float*)d_in[2];
    const float* W1 = (const float*)d_in[3];
    const float* W2 = (const float*)d_in[4];

    _Float16* W1q = (_Float16*)d_ws;                       // 128 KB
    _Float16* W1k = (_Float16*)((char*)d_ws + 128 * 1024); // 128 KB

    prep_w1<<<(HDIM * 256) / (256 * 4), 256, 0, stream>>>(W1, W1q, W1k);
    fused_kernel<<<NBLK, 512, 0, stream>>>(q, k, v, W1q, W1k, W2, (float*)d_out);
}